// Round 4
// baseline (97.565 us; speedup 1.0000x reference)
//
#include <hip/hip_runtime.h>
#include <hip/hip_bf16.h>
#include <stdint.h>

// Problem constants (fixed by the reference)
#define P 2048       // D_STATE
#define HN 64        // D_INPUT
#define L 16384      // kernel_size
#define BN 128       // l-columns per block (4 col-groups of 32)
#define KTW 16       // kt steps per wave (64 kt per K-half / 4 kt-groups)

typedef __bf16 bf16_t;
typedef bf16_t bf16x8 __attribute__((ext_vector_type(8)));
typedef float f32x16 __attribute__((ext_vector_type(16)));

__device__ __forceinline__ float2 cmul(float2 a, float2 b) {
    return make_float2(a.x * b.x - a.y * b.y, a.x * b.y + a.y * b.x);
}

__device__ __forceinline__ uint32_t packbf(float2 v) {
    union { __hip_bfloat162 v; uint32_t u; } cv;
    cv.v = __float22bfloat162_rn(make_float2(v.x, v.y));
    return cv.u;
}

// ---------------------------------------------------------------------------
// Prep: (a) W in bf16 32x32-MFMA A-fragment order: granule gid =
// ((kt*2+q)*2+mt)*64+lane holds A[m=mt*32+(lane&31)][k-run], p-run =
// kt*16 + q*8 + (lane>>5)*4, elements (W_re, -W_im) pairs (k=2p, 2p+1).
// (b) Tcol[p*32 + lc] = A_p^lc (float2), lc in [0,32) — block-invariant.
// (c) a32[p] = A_p^32.
// (d) abase[j*P + p] = A_p^(64j), j in [0,256) — binary exponentiation.
// (e) zero out (main accumulates into it with atomics).
__global__ void mv_prep(const float* __restrict__ Win,
                        const float* __restrict__ Ain,
                        uint4* __restrict__ wexp,
                        float2* __restrict__ tcol,
                        float2* __restrict__ a32,
                        float2* __restrict__ abase,
                        float4* __restrict__ outz) {
    int gid = blockIdx.x * 256 + threadIdx.x;   // 32768
    {   // wexp
        int lane = gid & 63;
        int mt = (gid >> 6) & 1;
        int q = (gid >> 7) & 1;
        int kt = gid >> 8;
        int m = mt * 32 + (lane & 31);
        int p0 = kt * 16 + q * 8 + (lane >> 5) * 4;
        const float4* wp = (const float4*)(Win + (size_t)(m * P + p0) * 2);
        float4 f0 = wp[0], f1 = wp[1];
        float re[4] = {f0.x, f0.z, f1.x, f1.z};
        float im[4] = {f0.y, f0.w, f1.y, f1.w};
        uint32_t o[4];
#pragma unroll
        for (int j = 0; j < 4; ++j)
            o[j] = packbf(make_float2(re[j], -im[j]));
        wexp[gid] = make_uint4(o[0], o[1], o[2], o[3]);
    }
    {   // Tcol: thread handles p = gid>>4, lc = 2*(gid&15) and lc+1
        int p = gid >> 4;
        int e = gid & 15;                      // lc/2
        float2 a = *(const float2*)(Ain + 2 * p);
        float2 a2 = cmul(a, a);
        float2 r = make_float2(1.f, 0.f);
        float2 sq = a2;
#pragma unroll
        for (int b = 0; b < 4; ++b) {
            if ((e >> b) & 1) r = cmul(r, sq);
            sq = cmul(sq, sq);
        }
        float2 ro = cmul(r, a);
        tcol[(size_t)p * 32 + 2 * e] = r;       // A^(2e)
        tcol[(size_t)p * 32 + 2 * e + 1] = ro;  // A^(2e+1)
        if (e == 15) a32[p] = cmul(ro, a);      // A^32
    }
    {   // abase: thread handles p = gid&2047, j in [16*(gid>>11), +16)
        int p = gid & 2047;
        int j16 = gid >> 11;                   // 0..15
        float2 a = *(const float2*)(Ain + 2 * p);
        float2 s = cmul(a, a);                 // A^2
#pragma unroll
        for (int i = 0; i < 5; ++i) s = cmul(s, s);   // A^64
        float2 a64v = s;
        float2 t1k = a64v;
#pragma unroll
        for (int i = 0; i < 4; ++i) t1k = cmul(t1k, t1k);  // A^1024
        float2 r = make_float2(1.f, 0.f);
        float2 sq = t1k;
#pragma unroll
        for (int b = 0; b < 4; ++b) {          // r = (A^1024)^j16
            if ((j16 >> b) & 1) r = cmul(r, sq);
            sq = cmul(sq, sq);
        }
        float2* ab = abase + (size_t)(j16 * 16) * P + p;
#pragma unroll
        for (int i = 0; i < 16; ++i) {
            ab[(size_t)i * P] = r;             // A^(64*(j16*16+i))
            r = cmul(r, a64v);
        }
    }
    {   // zero out: 1M floats = 262144 float4 = 8 x 32768
        float4 z = make_float4(0.f, 0.f, 0.f, 0.f);
#pragma unroll
        for (int i = 0; i < 8; ++i)
            outz[(size_t)i * 32768 + gid] = z;
    }
}

// ---------------------------------------------------------------------------
// Main: grid 256 = 128 col-blocks x 2 K-halves; 1024 thr = 16 waves
// (4 waves/SIMD). Block (bn, kb): cols [128bn, 128bn+128), p-half kb.
// Wave w: kt-group kg = w&3 (16 kt), col-group g = w>>2 (32 cols), BOTH
// m-tiles (acc[2] = 32 VGPR; lean budget, no spill at the 128 cap).
// The 4 g-waves of a kt-group read identical wexp/tcol addresses (L1
// dedupe). B-frags = LDS Base_g x reg Tcol. 4-way kt-group reduction in
// LDS, then f32 atomicAdd into out (2 contributors -> exact/deterministic).
__global__ void __launch_bounds__(1024, 4) mv_main(
    const uint4* __restrict__ wexp,
    const float2* __restrict__ Tcol,
    const float2* __restrict__ A32,
    const float2* __restrict__ Abase,
    float* __restrict__ out) {
    __shared__ __align__(16) float lds[16384];   // 64 KB: Base[4][1024] -> Red

    const int t = threadIdx.x;
    const int bn = blockIdx.x >> 1;    // col-block (0..127)
    const int kb = blockIdx.x & 1;     // K-half
    const int w = t >> 6;
    const int lw = t & 63;
    const int kg = w & 3;              // kt-group
    const int g = w >> 2;              // col-group (0..3)
    const int n = lw & 31;             // column within 32-wide tile
    const int kh = lw >> 5;            // k-half of the fragment

    float2* Base = (float2*)lds;       // [4][1024]: A_p^(128bn + 32g)

    {   // Base build: table load + 3 cmuls (no transcendentals)
        int p = kb * 1024 + t;
        float2 b = Abase[(size_t)(2 * bn) * P + p];
        float2 a32v = A32[p];
        Base[t] = b;
        b = cmul(b, a32v); Base[1024 + t] = b;
        b = cmul(b, a32v); Base[2048 + t] = b;
        b = cmul(b, a32v); Base[3072 + t] = b;
    }
    __syncthreads();

    const float4* Bg = (const float4*)(Base + g * 1024);
    const float2* tc = Tcol + n;
    const int ktbase = kb * 64 + kg * KTW;

    f32x16 acc[2];                     // [mt]
#pragma unroll
    for (int mt = 0; mt < 2; ++mt)
#pragma unroll
        for (int r = 0; r < 16; ++r) acc[mt][r] = 0.f;

#pragma unroll
    for (int i = 0; i < KTW; ++i) {
        const int kt = ktbase + i;
        const int lkt = kg * KTW + i;          // kt local to this K-half
        // loads (compiler pipelines across unrolled iterations)
        uint4 a0q[2], a1q[2];                  // [q] for mt=0/1
        float2 tv[8];
#pragma unroll
        for (int q = 0; q < 2; ++q) {
            a0q[q] = wexp[(size_t)(((kt * 2 + q) * 2 + 0) * 64 + lw)];
            a1q[q] = wexp[(size_t)(((kt * 2 + q) * 2 + 1) * 64 + lw)];
            int pb = kt * 16 + q * 8 + kh * 4;
#pragma unroll
            for (int j = 0; j < 4; ++j)
                tv[q * 4 + j] = tc[(size_t)(pb + j) * 32];
        }
#pragma unroll
        for (int q = 0; q < 2; ++q) {
            int bi = lkt * 8 + q * 4 + kh * 2;  // float4 idx into Bg
            float4 c0 = Bg[bi], c1 = Bg[bi + 1];
            uint32_t f[4];
            f[0] = packbf(cmul(make_float2(c0.x, c0.y), tv[q * 4 + 0]));
            f[1] = packbf(cmul(make_float2(c0.z, c0.w), tv[q * 4 + 1]));
            f[2] = packbf(cmul(make_float2(c1.x, c1.y), tv[q * 4 + 2]));
            f[3] = packbf(cmul(make_float2(c1.z, c1.w), tv[q * 4 + 3]));
            union { uint4 u; bf16x8 v; } F, A0, A1;
            F.u = make_uint4(f[0], f[1], f[2], f[3]);
            A0.u = a0q[q];
            A1.u = a1q[q];
            acc[0] = __builtin_amdgcn_mfma_f32_32x32x16_bf16(A0.v, F.v, acc[0], 0, 0, 0);
            acc[1] = __builtin_amdgcn_mfma_f32_32x32x16_bf16(A1.v, F.v, acc[1], 0, 0, 0);
        }
    }

    // ---- 4-way kt-group reduction per col-group, then atomic K-combine ----
    __syncthreads();                   // Base dead, reuse as Red
    float* Red = lds;                  // 16 waves x 1024 floats = 64 KB
    // C/D layout (m74): col = lane&31, row = (r&3) + 8*(r>>2) + 4*(lane>>5)
    const int gp = t >> 8;             // col-group this thread reduces
    const int s = t & 255;
    const int cp = (s & 15) * 2;       // even column within 32
    const int r0w = s >> 4;            // rows r0w and r0w+16

#pragma unroll
    for (int mt = 0; mt < 2; ++mt) {
#pragma unroll
        for (int r = 0; r < 16; ++r)
            Red[w * 1024 + r * 64 + lw] = acc[mt][r];
        __syncthreads();
#pragma unroll
        for (int ri = 0; ri < 2; ++ri) {
            int row = r0w + ri * 16;
            int rr = (row & 3) | ((row >> 3) << 2);
            int lane0 = cp + ((row >> 2) & 1) * 32;
            float sx = 0.f, sy = 0.f;
#pragma unroll
            for (int kk = 0; kk < 4; ++kk) {
                int base = (gp * 4 + kk) * 1024 + rr * 64 + lane0;
                sx += Red[base];
                sy += Red[base + 1];
            }
            size_t oidx = (size_t)(mt * 32 + row) * L + (size_t)bn * BN + gp * 32 + cp;
            atomicAdd(out + oidx, sx);
            atomicAdd(out + oidx + 1, sy);
        }
        __syncthreads();
    }
}

// ---------------------------------------------------------------------------
extern "C" void kernel_launch(void* const* d_in, const int* in_sizes, int n_in,
                              void* d_out, int out_size, void* d_ws, size_t ws_size,
                              hipStream_t stream) {
    const float* Ain = nullptr;
    const float* Win = nullptr;
    for (int i = 0; i < n_in; ++i) {
        if (in_sizes[i] == 2 * P) Ain = (const float*)d_in[i];
        else if (in_sizes[i] == 2 * HN * P) Win = (const float*)d_in[i];
    }
    if (!Ain) Ain = (const float*)d_in[0];
    if (!Win) Win = (const float*)d_in[1];
    (void)out_size; (void)ws_size;
    uint4* wexp = (uint4*)d_ws;                                  // 512 KB
    float2* tcol = (float2*)((char*)d_ws + 512 * 1024);          // +512 KB
    float2* a32 = (float2*)((char*)d_ws + 1024 * 1024);          // +16 KB
    float2* abase = (float2*)((char*)d_ws + 2 * 1024 * 1024);    // +4 MB
    mv_prep<<<128, 256, 0, stream>>>(Win, Ain, wexp, tcol, a32, abase,
                                     (float4*)d_out);
    mv_main<<<256, 1024, 0, stream>>>(wexp, tcol, a32, abase, (float*)d_out);
}

// Round 5
// 87.470 us; speedup vs baseline: 1.1154x; 1.1154x over previous
//
#include <hip/hip_runtime.h>
#include <hip/hip_bf16.h>
#include <stdint.h>

// Problem constants (fixed by the reference)
#define P 2048       // D_STATE
#define HN 64        // D_INPUT
#define L 16384      // kernel_size
#define KQ 4         // K split across blocks (k-quarters)
#define NT 8         // tiles per block (32 cols each -> 256 cols/block)
#define KTWV 4       // kt steps per wave (32 kt per quarter / 8 waves)
#define HL (HN * L)  // 1048576 floats per partial

typedef __bf16 bf16_t;
typedef bf16_t bf16x8 __attribute__((ext_vector_type(8)));
typedef float f32x16 __attribute__((ext_vector_type(16)));

__device__ __forceinline__ float2 cmul(float2 a, float2 b) {
    return make_float2(a.x * b.x - a.y * b.y, a.x * b.y + a.y * b.x);
}

__device__ __forceinline__ uint32_t packbf(float2 v) {
    union { __hip_bfloat162 v; uint32_t u; } cv;
    cv.v = __float22bfloat162_rn(make_float2(v.x, v.y));
    return cv.u;
}

// ---------------------------------------------------------------------------
// Prep: (a) W in bf16 32x32-MFMA A-fragment order: granule gid =
// ((kt*2+q)*2+mt)*64+lane holds A[m=mt*32+(lane&31)][k-run], p-run =
// kt*16 + q*8 + (lane>>5)*4, elements (W_re, -W_im) pairs (k=2p, 2p+1).
// (b) Tcol[p*32 + lc] = A_p^lc (float2), lc in [0,32) — block-invariant.
// (c) a32[p] = A_p^32.
// (d) abase[j*P + p] = A_p^(64j), j in [0,256) — binary exponentiation.
__global__ void mv_prep(const float* __restrict__ Win,
                        const float* __restrict__ Ain,
                        uint4* __restrict__ wexp,
                        float2* __restrict__ tcol,
                        float2* __restrict__ a32,
                        float2* __restrict__ abase) {
    int gid = blockIdx.x * 256 + threadIdx.x;   // 32768
    {   // wexp
        int lane = gid & 63;
        int mt = (gid >> 6) & 1;
        int q = (gid >> 7) & 1;
        int kt = gid >> 8;
        int m = mt * 32 + (lane & 31);
        int p0 = kt * 16 + q * 8 + (lane >> 5) * 4;
        const float4* wp = (const float4*)(Win + (size_t)(m * P + p0) * 2);
        float4 f0 = wp[0], f1 = wp[1];
        float re[4] = {f0.x, f0.z, f1.x, f1.z};
        float im[4] = {f0.y, f0.w, f1.y, f1.w};
        uint32_t o[4];
#pragma unroll
        for (int j = 0; j < 4; ++j)
            o[j] = packbf(make_float2(re[j], -im[j]));
        wexp[gid] = make_uint4(o[0], o[1], o[2], o[3]);
    }
    {   // Tcol: thread handles p = gid>>4, lc = 2*(gid&15) and lc+1
        int p = gid >> 4;
        int e = gid & 15;                      // lc/2
        float2 a = *(const float2*)(Ain + 2 * p);
        float2 a2 = cmul(a, a);
        float2 r = make_float2(1.f, 0.f);
        float2 sq = a2;
#pragma unroll
        for (int b = 0; b < 4; ++b) {
            if ((e >> b) & 1) r = cmul(r, sq);
            sq = cmul(sq, sq);
        }
        float2 ro = cmul(r, a);
        tcol[(size_t)p * 32 + 2 * e] = r;       // A^(2e)
        tcol[(size_t)p * 32 + 2 * e + 1] = ro;  // A^(2e+1)
        if (e == 15) a32[p] = cmul(ro, a);      // A^32
    }
    {   // abase: thread handles p = gid&2047, j in [16*(gid>>11), +16)
        int p = gid & 2047;
        int j16 = gid >> 11;                   // 0..15
        float2 a = *(const float2*)(Ain + 2 * p);
        float2 s = cmul(a, a);                 // A^2
#pragma unroll
        for (int i = 0; i < 5; ++i) s = cmul(s, s);   // A^64
        float2 a64v = s;
        float2 t1k = a64v;
#pragma unroll
        for (int i = 0; i < 4; ++i) t1k = cmul(t1k, t1k);  // A^1024
        float2 r = make_float2(1.f, 0.f);
        float2 sq = t1k;
#pragma unroll
        for (int b = 0; b < 4; ++b) {          // r = (A^1024)^j16
            if ((j16 >> b) & 1) r = cmul(r, sq);
            sq = cmul(sq, sq);
        }
        float2* ab = abase + (size_t)(j16 * 16) * P + p;
#pragma unroll
        for (int i = 0; i < 16; ++i) {
            ab[(size_t)i * P] = r;             // A^(64*(j16*16+i))
            r = cmul(r, a64v);
        }
    }
}

// ---------------------------------------------------------------------------
// Main: grid 256 = KQ(4) x 64 col-groups; 512 thr (8 waves, <=256 VGPR so
// the burst-loaded register K-slice is NOT squeezed out). Block (kq, cg):
// kt in [32kq, 32kq+32), cols [256cg, 256cg+256) as 8 tiles of 32.
// Wave w: 4 kt held ENTIRELY in registers (wreg 64 + tv 64 VGPR), loaded
// in one latency-amortized burst. Tile loop has ZERO global loads and
// ZERO base-advance barriers (all 8 tile base columns built upfront in
// LDS). Per-tile 8-way cross-wave K-reduction via padded Red; partials
// to ws; mv_reduce sums the 4 quarters (deterministic, no atomics).
__global__ void __launch_bounds__(512, 2) mv_main(
    const uint4* __restrict__ wexp,
    const float2* __restrict__ Tcol,
    const float2* __restrict__ A32,
    const float2* __restrict__ Abase,
    float* __restrict__ part) {
    __shared__ __align__(16) float2 BaseAll[NT * 512];   // 32 KB
    __shared__ float Red[8 * 1056];                      // 33 KB (padded)

    const int t = threadIdx.x;
    const int kq = blockIdx.x & 3;
    const int cg = blockIdx.x >> 2;        // 0..63
    const int w = t >> 6;
    const int lw = t & 63;
    const int n = lw & 31;                 // column within 32-wide tile
    const int kh = lw >> 5;                // k-half of the fragment

    // ---- burst-load register-resident K-slice ----
    uint4 wreg[KTWV][2][2];                // [kk][mt][q]
    float2 tv[KTWV][8];                    // [kk][q*4+j]
    {
        const float2* tc = Tcol + n;
#pragma unroll
        for (int kk = 0; kk < KTWV; ++kk) {
            int kt = kq * 32 + w * KTWV + kk;
#pragma unroll
            for (int q = 0; q < 2; ++q) {
#pragma unroll
                for (int mt = 0; mt < 2; ++mt)
                    wreg[kk][mt][q] = wexp[(size_t)(((kt * 2 + q) * 2 + mt) * 64 + lw)];
                int pb = kt * 16 + q * 8 + kh * 4;
#pragma unroll
                for (int jj = 0; jj < 4; ++jj)
                    tv[kk][q * 4 + jj] = tc[(size_t)(pb + jj) * 32];
            }
        }
    }

    {   // ---- all 8 tile base columns upfront (table load + 7 cmuls) ----
        int pg = kq * 512 + t;             // this block's p (512 of them)
        float2 b = Abase[(size_t)(4 * cg) * P + pg];   // A_p^(256cg)
        float2 a32v = A32[pg];
#pragma unroll
        for (int j = 0; j < NT; ++j) {
            BaseAll[j * 512 + t] = b;      // A_p^(256cg + 32j)
            b = cmul(b, a32v);
        }
    }
    __syncthreads();

    // epilogue index helpers (C/D layout m74: col = lane&31,
    // row = (r&3) + 8*(r>>2) + 4*(lane>>5))
    const int row = t >> 4;                // 0..31
    const int cp = (t & 15) * 2;           // even column within 32
    const int rr = (row & 3) | ((row >> 3) << 2);
    const int lane0 = cp + ((row >> 2) & 1) * 32;

    for (int j = 0; j < NT; ++j) {
        f32x16 acc0, acc1;                 // [mt]
#pragma unroll
        for (int r = 0; r < 16; ++r) { acc0[r] = 0.f; acc1[r] = 0.f; }
        const float4* Bj = (const float4*)(BaseAll + j * 512);

#pragma unroll
        for (int kk = 0; kk < KTWV; ++kk) {
#pragma unroll
            for (int q = 0; q < 2; ++q) {
                int bi = (w * KTWV + kk) * 8 + q * 4 + kh * 2;
                float4 c0 = Bj[bi], c1 = Bj[bi + 1];
                uint32_t f[4];
                f[0] = packbf(cmul(make_float2(c0.x, c0.y), tv[kk][q * 4 + 0]));
                f[1] = packbf(cmul(make_float2(c0.z, c0.w), tv[kk][q * 4 + 1]));
                f[2] = packbf(cmul(make_float2(c1.x, c1.y), tv[kk][q * 4 + 2]));
                f[3] = packbf(cmul(make_float2(c1.z, c1.w), tv[kk][q * 4 + 3]));
                union { uint4 u; bf16x8 v; } F, A0, A1;
                F.u = make_uint4(f[0], f[1], f[2], f[3]);
                A0.u = wreg[kk][0][q];
                A1.u = wreg[kk][1][q];
                acc0 = __builtin_amdgcn_mfma_f32_32x32x16_bf16(A0.v, F.v, acc0, 0, 0, 0);
                acc1 = __builtin_amdgcn_mfma_f32_32x32x16_bf16(A1.v, F.v, acc1, 0, 0, 0);
            }
        }

        // ---- per-tile 8-way cross-wave K-reduction (Red disjoint from
        // BaseAll: no extra sync needed around Base reads) ----
#pragma unroll
        for (int mt = 0; mt < 2; ++mt) {
#pragma unroll
            for (int r = 0; r < 16; ++r)
                Red[w * 1056 + r * 66 + lw] = mt ? acc1[r] : acc0[r];
            __syncthreads();
            float sx = 0.f, sy = 0.f;
#pragma unroll
            for (int ww = 0; ww < 8; ++ww) {
                int base = ww * 1056 + rr * 66 + lane0;
                sx += Red[base];
                sy += Red[base + 1];
            }
            *(float2*)(part + (size_t)kq * HL + (size_t)(mt * 32 + row) * L
                       + cg * 256 + j * 32 + cp) = make_float2(sx, sy);
            __syncthreads();
        }
    }
}

// ---------------------------------------------------------------------------
// Reduce: out[i] = sum over 4 k-quarters of partials. 4 MB out, 16 MB in.
__global__ void mv_reduce(const float4* __restrict__ part,
                          float4* __restrict__ out) {
    int i = blockIdx.x * 256 + threadIdx.x;      // 262144 float4
    float4 a = part[i];
    float4 b = part[i + (HL / 4)];
    float4 c = part[i + 2 * (HL / 4)];
    float4 d = part[i + 3 * (HL / 4)];
    out[i] = make_float4(a.x + b.x + c.x + d.x, a.y + b.y + c.y + d.y,
                         a.z + b.z + c.z + d.z, a.w + b.w + c.w + d.w);
}

// ---------------------------------------------------------------------------
extern "C" void kernel_launch(void* const* d_in, const int* in_sizes, int n_in,
                              void* d_out, int out_size, void* d_ws, size_t ws_size,
                              hipStream_t stream) {
    const float* Ain = nullptr;
    const float* Win = nullptr;
    for (int i = 0; i < n_in; ++i) {
        if (in_sizes[i] == 2 * P) Ain = (const float*)d_in[i];
        else if (in_sizes[i] == 2 * HN * P) Win = (const float*)d_in[i];
    }
    if (!Ain) Ain = (const float*)d_in[0];
    if (!Win) Win = (const float*)d_in[1];
    (void)out_size; (void)ws_size;
    uint4* wexp = (uint4*)d_ws;                                  // 512 KB
    float2* tcol = (float2*)((char*)d_ws + 512 * 1024);          // +512 KB
    float2* a32 = (float2*)((char*)d_ws + 1024 * 1024);          // +16 KB
    float2* abase = (float2*)((char*)d_ws + 2 * 1024 * 1024);    // +4 MB
    float* part = (float*)((char*)d_ws + 8 * 1024 * 1024);       // +16 MB
    mv_prep<<<128, 256, 0, stream>>>(Win, Ain, wexp, tcol, a32, abase);
    mv_main<<<256, 512, 0, stream>>>(wexp, tcol, a32, abase, part);
    mv_reduce<<<1024, 256, 0, stream>>>((const float4*)part, (float4*)d_out);
}